// Round 1
// baseline (137.844 us; speedup 1.0000x reference)
//
#include <hip/hip_runtime.h>

// CNF vector field + exact divergence via bilinear-form trick.
//   dx  = tanh(tanh([x,t]W1+b1)W2+b2)W3+b3, /2
//   div = 0.5 * d1^T (W2 ∘ (W1[:64]^T W3^T)) d2   (G precomputed, batch-free)
// One G-precompute kernel + one fused kernel: 256 blocks x 512 thr, 8 samples/block.

constexpr int HD = 512;       // hidden
constexpr int DD = 64;        // data dim
constexpr int SB = 8;         // samples per block
constexpr int NB = 2048 / SB; // 256 blocks

__global__ __launch_bounds__(512) void cnf_g_kernel(
    const float* __restrict__ W1, const float* __restrict__ W2,
    const float* __restrict__ W3, float* __restrict__ G)
{
    const int j = blockIdx.x;     // hidden-1 index
    const int m = threadIdx.x;    // hidden-2 index
    __shared__ float w1c[DD];
    if (threadIdx.x < DD) w1c[threadIdx.x] = W1[threadIdx.x * HD + j];
    __syncthreads();
    const float4* w3r = reinterpret_cast<const float4*>(W3 + m * DD);
    float s = 0.f;
#pragma unroll
    for (int i4 = 0; i4 < DD / 4; ++i4) {
        float4 w = w3r[i4];
        s += w1c[4*i4+0]*w.x + w1c[4*i4+1]*w.y + w1c[4*i4+2]*w.z + w1c[4*i4+3]*w.w;
    }
    G[j*HD + m] = W2[j*HD + m] * s;
}

__global__ __launch_bounds__(512) void cnf_fused_kernel(
    const float* __restrict__ tptr, const float* __restrict__ x,
    const float* __restrict__ W1, const float* __restrict__ b1,
    const float* __restrict__ W2, const float* __restrict__ b2,
    const float* __restrict__ W3, const float* __restrict__ b3,
    const float* __restrict__ G, float* __restrict__ out)
{
    // Activations sample-innermost: [unit][8 samples] -> 2x float4 broadcast reads.
    __shared__ float4 xsv[65 * 2];        // [i][s]  (i<65, s<8)
    __shared__ float4 h1v[HD * 2];        // [j][s]; reused as opart in phase 4
    __shared__ float4 d1v[HD * 2];        // [j][s]
    __shared__ float4 h2v[HD * 2];        // [m][s]
    __shared__ float divred[8][SB];

    const int tid = threadIdx.x;
    const int s0  = blockIdx.x * SB;

    // ---- phase 0: stage x rows (drop col 64, append t) ----
    {
        const float tval = tptr[0];
        for (int e = tid; e < SB * 65; e += 512) {
            int s = e / 65, i = e % 65;
            reinterpret_cast<float*>(xsv)[i * SB + s] =
                (i == DD) ? tval : x[(s0 + s) * 65 + i];
        }
    }
    __syncthreads();

    // ---- phase 1: layer 1; thread = hidden unit j ----
    {
        float2 acc[4];
        const float bb = b1[tid];
#pragma unroll
        for (int p = 0; p < 4; ++p) acc[p] = make_float2(bb, bb);
#pragma unroll 5
        for (int i = 0; i < 65; ++i) {
            float w = W1[i * HD + tid];
            float4 a = xsv[2*i], b = xsv[2*i + 1];
            acc[0].x += a.x*w; acc[0].y += a.y*w;
            acc[1].x += a.z*w; acc[1].y += a.w*w;
            acc[2].x += b.x*w; acc[2].y += b.y*w;
            acc[3].x += b.z*w; acc[3].y += b.w*w;
        }
        float h[8], d[8];
#pragma unroll
        for (int p = 0; p < 4; ++p) { h[2*p] = tanhf(acc[p].x); h[2*p+1] = tanhf(acc[p].y); }
#pragma unroll
        for (int q = 0; q < 8; ++q) d[q] = 1.f - h[q]*h[q];
        h1v[2*tid]   = make_float4(h[0], h[1], h[2], h[3]);
        h1v[2*tid+1] = make_float4(h[4], h[5], h[6], h[7]);
        d1v[2*tid]   = make_float4(d[0], d[1], d[2], d[3]);
        d1v[2*tid+1] = make_float4(d[4], d[5], d[6], d[7]);
    }
    __syncthreads();

    // ---- phase 2+3 fused: layer 2 AND div matvec share one j-loop ----
    float divpart[8];
    {
        float2 acc[4], vac[4];
        const float bb = b2[tid];
#pragma unroll
        for (int p = 0; p < 4; ++p) { acc[p] = make_float2(bb, bb); vac[p] = make_float2(0.f, 0.f); }
        const float* W2c = W2 + tid;
        const float* Gc  = G  + tid;
#pragma unroll 4
        for (int j = 0; j < HD; ++j) {
            float w = W2c[j * HD];
            float g = Gc[j * HD];
            float4 ha = h1v[2*j], hb = h1v[2*j + 1];
            float4 da = d1v[2*j], db = d1v[2*j + 1];
            acc[0].x += ha.x*w; acc[0].y += ha.y*w;
            acc[1].x += ha.z*w; acc[1].y += ha.w*w;
            acc[2].x += hb.x*w; acc[2].y += hb.y*w;
            acc[3].x += hb.z*w; acc[3].y += hb.w*w;
            vac[0].x += da.x*g; vac[0].y += da.y*g;
            vac[1].x += da.z*g; vac[1].y += da.w*g;
            vac[2].x += db.x*g; vac[2].y += db.y*g;
            vac[3].x += db.z*g; vac[3].y += db.w*g;
        }
        float h[8];
#pragma unroll
        for (int p = 0; p < 4; ++p) { h[2*p] = tanhf(acc[p].x); h[2*p+1] = tanhf(acc[p].y); }
        h2v[2*tid]   = make_float4(h[0], h[1], h[2], h[3]);
        h2v[2*tid+1] = make_float4(h[4], h[5], h[6], h[7]);
        float v[8] = {vac[0].x, vac[0].y, vac[1].x, vac[1].y,
                      vac[2].x, vac[2].y, vac[3].x, vac[3].y};
#pragma unroll
        for (int q = 0; q < 8; ++q) divpart[q] = v[q] * (1.f - h[q]*h[q]);
    }
    // block-reduce div over 512 threads (8 waves)
    {
#pragma unroll
        for (int q = 0; q < 8; ++q) {
            float v = divpart[q];
            for (int off = 32; off > 0; off >>= 1) v += __shfl_down(v, off);
            divpart[q] = v;
        }
        const int wave = tid >> 6, lane = tid & 63;
        if (lane == 0) {
#pragma unroll
            for (int q = 0; q < 8; ++q) divred[wave][q] = divpart[q];
        }
    }
    __syncthreads();   // also fences h1v reads -> safe to alias as opart below
    if (tid < SB) {
        float dsum = 0.f;
#pragma unroll
        for (int w = 0; w < 8; ++w) dsum += divred[w][tid];
        out[(s0 + tid) * 65 + DD] = 0.5f * dsum;
    }

    // ---- phase 4: layer 3; thread = (part, k), 8 partial sums over m ----
    {
        const int k = tid & 63, part = tid >> 6;
        float o[8];
#pragma unroll
        for (int q = 0; q < 8; ++q) o[q] = 0.f;
#pragma unroll 4
        for (int mm = 0; mm < 64; ++mm) {
            int m = part * 64 + mm;
            float w3 = W3[m * DD + k];
            float4 ha = h2v[2*m], hb = h2v[2*m + 1];
            o[0] += ha.x*w3; o[1] += ha.y*w3; o[2] += ha.z*w3; o[3] += ha.w*w3;
            o[4] += hb.x*w3; o[5] += hb.y*w3; o[6] += hb.z*w3; o[7] += hb.w*w3;
        }
        float* opart = reinterpret_cast<float*>(h1v);   // h1v dead, reuse
#pragma unroll
        for (int q = 0; q < 8; ++q) opart[part * 512 + q * 64 + k] = o[q];
    }
    __syncthreads();
    {
        const int s = tid >> 6, k = tid & 63;
        const float* opart = reinterpret_cast<const float*>(h1v);
        float sum = b3[k];
#pragma unroll
        for (int p = 0; p < 8; ++p) sum += opart[p * 512 + s * 64 + k];
        out[(s0 + s) * 65 + k] = 0.5f * sum;
    }
}

extern "C" void kernel_launch(void* const* d_in, const int* in_sizes, int n_in,
                              void* d_out, int out_size, void* d_ws, size_t ws_size,
                              hipStream_t stream) {
    const float* t  = (const float*)d_in[0];
    const float* x  = (const float*)d_in[1];
    const float* W1 = (const float*)d_in[2];
    const float* b1 = (const float*)d_in[3];
    const float* W2 = (const float*)d_in[4];
    const float* b2 = (const float*)d_in[5];
    const float* W3 = (const float*)d_in[6];
    const float* b3 = (const float*)d_in[7];
    float* out = (float*)d_out;
    float* G   = (float*)d_ws;             // 512*512*4 = 1 MB scratch

    cnf_g_kernel<<<HD, HD, 0, stream>>>(W1, W2, W3, G);
    cnf_fused_kernel<<<NB, HD, 0, stream>>>(t, x, W1, b1, W2, b2, W3, b3, G, out);
}

// Round 2
// 121.511 us; speedup vs baseline: 1.1344x; 1.1344x over previous
//
#include <hip/hip_runtime.h>

// CNF vector field + exact divergence via bilinear-form trick.
//   dx  = tanh(tanh([x,t]W1+b1)W2+b2)W3+b3, /2
//   div = 0.5 * d1^T (W2 ∘ (W1[:64]^T W3^T)) d2   (G precomputed, batch-free)
// R1: G kernel rewritten coalesced+LDS-tiled (was ~60us uncoalesced);
//     fused kernel 1024 thr/block (j-split layer2) for 16 waves/CU occupancy.

constexpr int HD = 512;       // hidden
constexpr int DD = 64;        // data dim
constexpr int SB = 8;         // samples per block
constexpr int NB = 2048 / SB; // 256 blocks

// ---------------- G = W2 ∘ (W1[:64]^T @ W3^T) ----------------
// grid 512 = 64 j-tiles x 8 m-tiles; block 512 thr = (jl<8, ml<64).
__global__ __launch_bounds__(512) void cnf_g_kernel(
    const float* __restrict__ W1, const float* __restrict__ W2,
    const float* __restrict__ W3, float* __restrict__ G)
{
    __shared__ float w1t[64 * 9];   // [i][jl], pad 9 -> broadcast reads
    __shared__ float w3t[64 * 65];  // [ml][i], pad 65 -> conflict-free
    const int tid = threadIdx.x;
    const int j0 = (blockIdx.x & 63) * 8;
    const int m0 = (blockIdx.x >> 6) * 64;
    {   // stage W1 tile (64 i x 8 j)
        int i = tid >> 3, jl = tid & 7;
        w1t[i * 9 + jl] = W1[i * HD + j0 + jl];
    }
    for (int e = tid; e < 64 * 64; e += 512) {  // stage W3 rows m0..m0+63, coalesced
        int ml = e >> 6, i = e & 63;
        w3t[ml * 65 + i] = W3[(m0 + ml) * DD + i];
    }
    __syncthreads();
    const int jl = tid >> 6, ml = tid & 63;
    float s = 0.f;
#pragma unroll
    for (int i = 0; i < 64; ++i)
        s += w1t[i * 9 + jl] * w3t[ml * 65 + i];   // broadcast x bank-spread
    const int j = j0 + jl, m = m0 + ml;
    G[j * HD + m] = W2[j * HD + m] * s;            // coalesced over m
}

// ---------------- fused MLP + divergence ----------------
// 1024 threads: u = tid&511 (unit), half = tid>>9.
// Layer2: half h reduces j in [256h, 256h+256); partials combined via LDS.
__global__ __launch_bounds__(1024) void cnf_fused_kernel(
    const float* __restrict__ tptr, const float* __restrict__ x,
    const float* __restrict__ W1, const float* __restrict__ b1,
    const float* __restrict__ W2, const float* __restrict__ b2,
    const float* __restrict__ W3, const float* __restrict__ b3,
    const float* __restrict__ G, float* __restrict__ out)
{
    __shared__ float4 xsv[65 * 2];       // [i][s] sample-innermost
    __shared__ float  sbuf[8192];        // 32KB: h1v+d1v -> P partials -> opart
    __shared__ float4 h2v[HD * 2];       // [m][s]
    __shared__ float  divred[8][8];

    float4* h1v = reinterpret_cast<float4*>(sbuf);          // [0..1023]
    float4* d1v = reinterpret_cast<float4*>(sbuf + 4096);   // [0..1023]

    const int tid  = threadIdx.x;
    const int s0   = blockIdx.x * SB;
    const int u    = tid & 511;
    const int half = tid >> 9;

    // ---- phase 0: stage x rows (drop col 64, append t) ----
    {
        const float tval = tptr[0];
        for (int e = tid; e < SB * 65; e += 1024) {
            int s = e / 65, i = e % 65;
            sbuf[0] = sbuf[0];  // no-op
            reinterpret_cast<float*>(xsv)[i * SB + s] =
                (i == DD) ? tval : x[(s0 + s) * 65 + i];
        }
    }
    __syncthreads();

    // ---- phase 1: layer 1; thread = (unit u, 4-sample group half) ----
    {
        const float bb = b1[u];
        float2 a0 = make_float2(bb, bb), a1 = make_float2(bb, bb);
#pragma unroll 5
        for (int i = 0; i < 65; ++i) {
            float w  = W1[i * HD + u];
            float4 a = xsv[2 * i + half];
            a0.x += a.x * w; a0.y += a.y * w;
            a1.x += a.z * w; a1.y += a.w * w;
        }
        float h0 = tanhf(a0.x), h1_ = tanhf(a0.y), h2_ = tanhf(a1.x), h3 = tanhf(a1.y);
        h1v[2 * u + half] = make_float4(h0, h1_, h2_, h3);
        d1v[2 * u + half] = make_float4(1.f - h0 * h0, 1.f - h1_ * h1_,
                                        1.f - h2_ * h2_, 1.f - h3 * h3);
    }
    __syncthreads();

    // ---- phase 2: layer 2 + div matvec, j-range split across halves ----
    float2 acc[4], vac[4];
    {
        const float bb = (half == 1) ? b2[u] : 0.f;
#pragma unroll
        for (int p = 0; p < 4; ++p) {
            acc[p] = make_float2(bb, bb);
            vac[p] = make_float2(0.f, 0.f);
        }
        const int jb = half * 256;
        const float* W2c = W2 + (size_t)jb * HD + u;
        const float* Gc  = G  + (size_t)jb * HD + u;
#pragma unroll 4
        for (int jj = 0; jj < 256; ++jj) {
            float w = W2c[(size_t)jj * HD];
            float g = Gc[(size_t)jj * HD];
            int j = jb + jj;
            float4 ha = h1v[2 * j], hb = h1v[2 * j + 1];
            float4 da = d1v[2 * j], db = d1v[2 * j + 1];
            acc[0].x += ha.x * w; acc[0].y += ha.y * w;
            acc[1].x += ha.z * w; acc[1].y += ha.w * w;
            acc[2].x += hb.x * w; acc[2].y += hb.y * w;
            acc[3].x += hb.z * w; acc[3].y += hb.w * w;
            vac[0].x += da.x * g; vac[0].y += da.y * g;
            vac[1].x += da.z * g; vac[1].y += da.w * g;
            vac[2].x += db.x * g; vac[2].y += db.y * g;
            vac[3].x += db.z * g; vac[3].y += db.w * g;
        }
    }
    __syncthreads();   // all h1v/d1v reads done -> sbuf reusable as P
    {
        float2* P = reinterpret_cast<float2*>(sbuf);   // [8][512] float2
        if (half == 0) {
#pragma unroll
            for (int p = 0; p < 4; ++p) {
                P[p * 512 + u]       = acc[p];
                P[(p + 4) * 512 + u] = vac[p];
            }
        }
        __syncthreads();
        if (half == 1) {
#pragma unroll
            for (int p = 0; p < 4; ++p) {
                float2 pa = P[p * 512 + u], pv = P[(p + 4) * 512 + u];
                acc[p].x += pa.x; acc[p].y += pa.y;
                vac[p].x += pv.x; vac[p].y += pv.y;
            }
            float h[8];
            h[0] = tanhf(acc[0].x); h[1] = tanhf(acc[0].y);
            h[2] = tanhf(acc[1].x); h[3] = tanhf(acc[1].y);
            h[4] = tanhf(acc[2].x); h[5] = tanhf(acc[2].y);
            h[6] = tanhf(acc[3].x); h[7] = tanhf(acc[3].y);
            h2v[2 * u]     = make_float4(h[0], h[1], h[2], h[3]);
            h2v[2 * u + 1] = make_float4(h[4], h[5], h[6], h[7]);
            float vt[8] = {vac[0].x, vac[0].y, vac[1].x, vac[1].y,
                           vac[2].x, vac[2].y, vac[3].x, vac[3].y};
            float dp[8];
#pragma unroll
            for (int q = 0; q < 8; ++q) dp[q] = vt[q] * (1.f - h[q] * h[q]);
#pragma unroll
            for (int q = 0; q < 8; ++q) {
                float v = dp[q];
                for (int off = 32; off > 0; off >>= 1) v += __shfl_down(v, off);
                dp[q] = v;
            }
            const int wv = (tid >> 6) & 7, lane = tid & 63;
            if (lane == 0) {
#pragma unroll
                for (int q = 0; q < 8; ++q) divred[wv][q] = dp[q];
            }
        }
    }
    __syncthreads();   // h2v + divred ready; sbuf free again (opart)
    if (tid < 8) {
        float ds = 0.f;
#pragma unroll
        for (int w = 0; w < 8; ++w) ds += divred[w][tid];
        out[(s0 + tid) * 65 + DD] = 0.5f * ds;
    }

    // ---- phase 4: layer 3; thread = (part<16, k<64), 32 m's per part ----
    {
        const int k = tid & 63, part = tid >> 6;
        float o[8];
#pragma unroll
        for (int q = 0; q < 8; ++q) o[q] = 0.f;
        const int mb = part * 32;
#pragma unroll 4
        for (int mm = 0; mm < 32; ++mm) {
            int m = mb + mm;
            float w3 = W3[m * DD + k];
            float4 ha = h2v[2 * m], hb = h2v[2 * m + 1];
            o[0] += ha.x * w3; o[1] += ha.y * w3; o[2] += ha.z * w3; o[3] += ha.w * w3;
            o[4] += hb.x * w3; o[5] += hb.y * w3; o[6] += hb.z * w3; o[7] += hb.w * w3;
        }
#pragma unroll
        for (int q = 0; q < 8; ++q) sbuf[part * 512 + q * 64 + k] = o[q];
    }
    __syncthreads();
    if (tid < 512) {
        const int s = tid >> 6, k = tid & 63;
        float sum = b3[k];
#pragma unroll
        for (int p = 0; p < 16; ++p) sum += sbuf[p * 512 + s * 64 + k];
        out[(s0 + s) * 65 + k] = 0.5f * sum;
    }
}

extern "C" void kernel_launch(void* const* d_in, const int* in_sizes, int n_in,
                              void* d_out, int out_size, void* d_ws, size_t ws_size,
                              hipStream_t stream) {
    const float* t  = (const float*)d_in[0];
    const float* x  = (const float*)d_in[1];
    const float* W1 = (const float*)d_in[2];
    const float* b1 = (const float*)d_in[3];
    const float* W2 = (const float*)d_in[4];
    const float* b2 = (const float*)d_in[5];
    const float* W3 = (const float*)d_in[6];
    const float* b3 = (const float*)d_in[7];
    float* out = (float*)d_out;
    float* G   = (float*)d_ws;             // 512*512*4 = 1 MB scratch

    cnf_g_kernel<<<512, 512, 0, stream>>>(W1, W2, W3, G);
    cnf_fused_kernel<<<NB, 1024, 0, stream>>>(t, x, W1, b1, W2, b2, W3, b3, G, out);
}